// Round 4
// baseline (419.895 us; speedup 1.0000x reference)
//
#include <hip/hip_runtime.h>
#include <hip/hip_bf16.h>

// Problem: B=16, C=512, L=1024.
// score[b,i,j] = sum_c k[b,c,i]*q[b,c,j] / 32 ; P = softmax over b (axis=0!)
// out[b,c,j] = sum_i v[b,c,i]*P[b,i,j]
// We compute S'[b][j][i] (transposed score) so that PV's B-operand (P'[j][i])
// is reduction(i)-contiguous. Softmax over b is elementwise in (j,i) -> lane-local.

#define LN 1024
#define CC 512
#define BN 16

typedef __attribute__((ext_vector_type(8))) short bf16x8;
typedef __attribute__((ext_vector_type(4))) float f32x4;

static __device__ __forceinline__ unsigned short f2bf(float x) {
  union { float f; unsigned u; } un; un.f = x;
  unsigned r = un.u + 0x7fffu + ((un.u >> 16) & 1u);   // RNE
  return (unsigned short)(r >> 16);
}

// ---------------- Kernel 0: transpose-convert q,k (f32 [b][c][l]) -> bf16 [b][l][c]
__global__ __launch_bounds__(256) void transpose_convert(
    const float* __restrict__ q, const float* __restrict__ k,
    unsigned short* __restrict__ qT, unsigned short* __restrict__ kT) {
  __shared__ float tile[32][33];
  const int b   = blockIdx.z >> 1;
  const int mat = blockIdx.z & 1;
  const float* src = mat ? k : q;
  unsigned short* dst = mat ? kT : qT;
  const int l0 = blockIdx.x * 32, c0 = blockIdx.y * 32;
  const int t = threadIdx.x;
  const int ll = t & 31, cbase = t >> 5;        // read: lanes contiguous in l
  const float* sp = src + ((size_t)b * CC + c0) * LN + l0;
#pragma unroll
  for (int r = 0; r < 4; ++r) {
    int cc = cbase + r * 8;
    tile[cc][ll] = sp[(size_t)cc * LN + ll];
  }
  __syncthreads();
  const int co = t & 31, lbase = t >> 5;        // write: lanes contiguous in c
  unsigned short* dp = dst + ((size_t)b * LN + l0) * CC + c0;
#pragma unroll
  for (int r = 0; r < 4; ++r) {
    int lo = lbase + r * 8;
    dp[(size_t)lo * CC + co] = f2bf(tile[co][lo]);
  }
}

// ---------------- Kernel 1: fused QK^T + softmax over batch
// Block: 32x32 (j,i) tile, 4 waves = 2x2 quadrants of 16x16.
// Each wave accumulates its 16x16 tile for ALL 16 batches -> softmax is lane-local.
__global__ __launch_bounds__(256) void qk_softmax(
    const unsigned short* __restrict__ qT,   // [b][j][c] bf16
    const unsigned short* __restrict__ kT,   // [b][i][c] bf16
    unsigned short* __restrict__ P) {        // [b][j][i] bf16
  const int it = blockIdx.x, jt = blockIdx.y;
  const int t = threadIdx.x, w = t >> 6, l = t & 63;
  const int wj = w >> 1, wi = w & 1;
  const int jb = jt * 32 + wj * 16;   // M base (j)
  const int ib = it * 32 + wi * 16;   // N base (i)
  const int lr = l & 15;              // row/col within fragment
  const int lk = (l >> 4) * 8;        // k-offset within fragment

  const unsigned short* qrow = qT + ((size_t)(jb + lr)) * CC + lk;
  const unsigned short* krow = kT + ((size_t)(ib + lr)) * CC + lk;

  f32x4 acc[BN];
#pragma unroll
  for (int b = 0; b < BN; ++b) acc[b] = (f32x4){0.f, 0.f, 0.f, 0.f};

#pragma unroll 1
  for (int c0 = 0; c0 < CC; c0 += 32) {
#pragma unroll
    for (int b = 0; b < BN; ++b) {
      bf16x8 av = *(const bf16x8*)(qrow + (size_t)b * LN * CC + c0);
      bf16x8 bv = *(const bf16x8*)(krow + (size_t)b * LN * CC + c0);
      acc[b] = __builtin_amdgcn_mfma_f32_16x16x32_bf16(av, bv, acc[b], 0, 0, 0);
    }
  }

  const float scale = 0.03125f;   // 1/sqrt(1024)
  const int i = ib + lr;          // D col = lane&15
#pragma unroll
  for (int r = 0; r < 4; ++r) {
    const int j = jb + (l >> 4) * 4 + r;   // D row = (lane>>4)*4 + reg
    float mx = -1e30f;
#pragma unroll
    for (int b = 0; b < BN; ++b) mx = fmaxf(mx, acc[b][r] * scale);
    float e[BN]; float s = 0.f;
#pragma unroll
    for (int b = 0; b < BN; ++b) { e[b] = __expf(acc[b][r] * scale - mx); s += e[b]; }
    const float inv = 1.f / s;
#pragma unroll
    for (int b = 0; b < BN; ++b)
      P[((size_t)b * LN + j) * LN + i] = f2bf(e[b] * inv);
  }
}

// ---------------- Kernel 2: out[b][c][j] = sum_i v[b][c][i] * P[b][j][i]
// Block: 64(c) x 64(j) tile per batch; 4 waves 2x2; each wave 32x32 via 2x2 frags.
__global__ __launch_bounds__(256) void pv(
    const float* __restrict__ v,             // [b][c][i] f32
    const unsigned short* __restrict__ P,    // [b][j][i] bf16
    float* __restrict__ out) {               // [b][c][j] f32
  const int jt = blockIdx.x, ct = blockIdx.y, b = blockIdx.z;
  const int t = threadIdx.x, w = t >> 6, l = t & 63;
  const int cb = ct * 64 + (w >> 1) * 32;
  const int jb = jt * 64 + (w & 1) * 32;
  const int lr = l & 15, lk = (l >> 4) * 8;

  f32x4 acc[2][2];
#pragma unroll
  for (int mm = 0; mm < 2; ++mm)
#pragma unroll
    for (int nn = 0; nn < 2; ++nn) acc[mm][nn] = (f32x4){0.f, 0.f, 0.f, 0.f};

  const float* vbase = v + ((size_t)b * CC) * LN;
  const unsigned short* pbase = P + ((size_t)b * LN) * LN;

#pragma unroll 1
  for (int i0 = 0; i0 < LN; i0 += 32) {
    bf16x8 a[2], bb[2];
#pragma unroll
    for (int mm = 0; mm < 2; ++mm) {
      const float* vp = vbase + (size_t)(cb + mm * 16 + lr) * LN + i0 + lk;
      float4 v0 = *(const float4*)vp;
      float4 v1 = *(const float4*)(vp + 4);
      bf16x8 av;
      av[0] = (short)f2bf(v0.x); av[1] = (short)f2bf(v0.y);
      av[2] = (short)f2bf(v0.z); av[3] = (short)f2bf(v0.w);
      av[4] = (short)f2bf(v1.x); av[5] = (short)f2bf(v1.y);
      av[6] = (short)f2bf(v1.z); av[7] = (short)f2bf(v1.w);
      a[mm] = av;
    }
#pragma unroll
    for (int nn = 0; nn < 2; ++nn)
      bb[nn] = *(const bf16x8*)(pbase + (size_t)(jb + nn * 16 + lr) * LN + i0 + lk);
#pragma unroll
    for (int mm = 0; mm < 2; ++mm)
#pragma unroll
      for (int nn = 0; nn < 2; ++nn)
        acc[mm][nn] = __builtin_amdgcn_mfma_f32_16x16x32_bf16(a[mm], bb[nn], acc[mm][nn], 0, 0, 0);
  }

#pragma unroll
  for (int mm = 0; mm < 2; ++mm)
#pragma unroll
    for (int nn = 0; nn < 2; ++nn)
#pragma unroll
      for (int r = 0; r < 4; ++r)
        out[((size_t)b * CC + cb + mm * 16 + (l >> 4) * 4 + r) * LN + jb + nn * 16 + lr]
            = acc[mm][nn][r];
}

extern "C" void kernel_launch(void* const* d_in, const int* in_sizes, int n_in,
                              void* d_out, int out_size, void* d_ws, size_t ws_size,
                              hipStream_t stream) {
  const float* q = (const float*)d_in[0];
  const float* k = (const float*)d_in[1];
  const float* v = (const float*)d_in[2];
  float* out = (float*)d_out;
  // ws layout (needs 64 MiB): qT 16MiB | kT 16MiB | P 32MiB
  unsigned short* qT = (unsigned short*)d_ws;
  unsigned short* kT = qT + (size_t)BN * LN * CC;
  unsigned short* P  = kT + (size_t)BN * LN * CC;

  transpose_convert<<<dim3(LN / 32, CC / 32, BN * 2), 256, 0, stream>>>(q, k, qT, kT);
  qk_softmax<<<dim3(LN / 32, LN / 32), 256, 0, stream>>>(qT, kT, P);
  pv<<<dim3(LN / 64, CC / 64, BN), 256, 0, stream>>>(v, P, out);
}

// Round 5
// 104.023 us; speedup vs baseline: 4.0366x; 4.0366x over previous
//
#include <hip/hip_runtime.h>
#include <hip/hip_bf16.h>

// B=16, C=512, L=1024.
// score[b,i,j] = sum_c k[b,c,i]*q[b,c,j] / 32 ; P = softmax over b (axis=0!)
// out[b,c,j] = sum_i v[b,c,i]*P[b,i,j]
// Pipeline (all bf16 MFMA, fp32 accum):
//   K0 transpose_convert: q,k f32 [b][c][l] -> qT,kT bf16 [b][l][c]
//   K1 gemm_bt: S'[b][j][i] = (qT . kT^T) / 32, bf16   (batched 1024x1024x512)
//   K3 convert_v: v f32 -> vB bf16 [b][c][i]  (overlays qT, dead after K1)
//   K2 softmax_b: in-place softmax over b (16 values per (j,i)) on S'
//   K4 gemm_bt: out[b][c][j] = vB . P^T, f32           (batched 512x1024x1024)
// ws = 64 MiB exactly: qT(16) | kT(16) | S'/P(32), vB overlays qT.

#define LN 1024
#define CC 512
#define BN 16

typedef __attribute__((ext_vector_type(8))) short bf16x8;
typedef __attribute__((ext_vector_type(4))) float f32x4;

static __device__ __forceinline__ unsigned short f2bf(float x) {
  union { float f; unsigned u; } un; un.f = x;
  unsigned r = un.u + 0x7fffu + ((un.u >> 16) & 1u);   // RNE
  return (unsigned short)(r >> 16);
}
static __device__ __forceinline__ float bf2f(unsigned short h) {
  union { unsigned u; float f; } un; un.u = ((unsigned)h) << 16; return un.f;
}

// ---------------- K0: transpose-convert q,k (f32 [b][c][l]) -> bf16 [b][l][c]
__global__ __launch_bounds__(256) void transpose_convert(
    const float* __restrict__ q, const float* __restrict__ k,
    unsigned short* __restrict__ qT, unsigned short* __restrict__ kT) {
  __shared__ float tile[32][33];
  const int b   = blockIdx.z >> 1;
  const int mat = blockIdx.z & 1;
  const float* src = mat ? k : q;
  unsigned short* dst = mat ? kT : qT;
  const int l0 = blockIdx.x * 32, c0 = blockIdx.y * 32;
  const int t = threadIdx.x;
  const int ll = t & 31, cbase = t >> 5;
  const float* sp = src + ((size_t)b * CC + c0) * LN + l0;
#pragma unroll
  for (int r = 0; r < 4; ++r) {
    int cc = cbase + r * 8;
    tile[cc][ll] = sp[(size_t)cc * LN + ll];
  }
  __syncthreads();
  const int co = t & 31, lbase = t >> 5;
  unsigned short* dp = dst + ((size_t)b * LN + l0) * CC + c0;
#pragma unroll
  for (int r = 0; r < 4; ++r) {
    int lo = lbase + r * 8;
    dp[(size_t)lo * CC + co] = f2bf(tile[co][lo]);
  }
}

// ---------------- batched GEMM, both operands K-contiguous ("BT" form):
// C[row][col] = scale * sum_k A[row][k] * B[col][k]
// block 128x128, BK=32, 4 waves (2x2), each wave 4x4 frags of 16x16x32.
// LDS rows padded to 40 shorts (80B) -> bank-balanced b128 access.
template<int KD, int LDAv, int LDBv, int LDCv, bool OBF>
__global__ __launch_bounds__(256) void gemm_bt(
    const unsigned short* __restrict__ A, const unsigned short* __restrict__ B,
    void* __restrict__ Cv, float scale,
    size_t strideA, size_t strideB, size_t strideC) {
  __shared__ unsigned short As[128 * 40];
  __shared__ unsigned short Bs[128 * 40];
  const int bz = blockIdx.z;
  const unsigned short* Ab = A + (size_t)bz * strideA;
  const unsigned short* Bb = B + (size_t)bz * strideB;
  const int tm = blockIdx.y, tn = blockIdx.x;
  const int t = threadIdx.x, w = t >> 6, l = t & 63;
  const int wr = w >> 1, wc = w & 1;
  const int lr = l & 15, lk8 = (l >> 4) * 8;

  f32x4 acc[4][4];
#pragma unroll
  for (int m = 0; m < 4; ++m)
#pragma unroll
    for (int n = 0; n < 4; ++n) acc[m][n] = (f32x4){0.f, 0.f, 0.f, 0.f};

  auto gA = [&](int q, int c0) -> bf16x8 {
    return *(const bf16x8*)(Ab + (size_t)(tm * 128 + (q >> 2)) * LDAv + c0 + (q & 3) * 8);
  };
  auto gB = [&](int q, int c0) -> bf16x8 {
    return *(const bf16x8*)(Bb + (size_t)(tn * 128 + (q >> 2)) * LDBv + c0 + (q & 3) * 8);
  };

  bf16x8 ra0 = gA(t, 0), ra1 = gA(t + 256, 0);
  bf16x8 rb0 = gB(t, 0), rb1 = gB(t + 256, 0);

  const int NSTEP = KD / 32;
#pragma unroll 1
  for (int step = 0; step < NSTEP; ++step) {
    __syncthreads();   // previous step's frag reads done
    *(bf16x8*)(&As[(t >> 2) * 40 + (t & 3) * 8]) = ra0;
    *(bf16x8*)(&As[((t + 256) >> 2) * 40 + (t & 3) * 8]) = ra1;
    *(bf16x8*)(&Bs[(t >> 2) * 40 + (t & 3) * 8]) = rb0;
    *(bf16x8*)(&Bs[((t + 256) >> 2) * 40 + (t & 3) * 8]) = rb1;
    if (step + 1 < NSTEP) {
      const int c0 = (step + 1) * 32;
      ra0 = gA(t, c0); ra1 = gA(t + 256, c0);
      rb0 = gB(t, c0); rb1 = gB(t + 256, c0);
    }
    __syncthreads();   // tile staged
    bf16x8 af[4], bfr[4];
#pragma unroll
    for (int m = 0; m < 4; ++m)
      af[m] = *(const bf16x8*)(&As[(wr * 64 + m * 16 + lr) * 40 + lk8]);
#pragma unroll
    for (int n = 0; n < 4; ++n)
      bfr[n] = *(const bf16x8*)(&Bs[(wc * 64 + n * 16 + lr) * 40 + lk8]);
#pragma unroll
    for (int m = 0; m < 4; ++m)
#pragma unroll
      for (int n = 0; n < 4; ++n)
        acc[m][n] = __builtin_amdgcn_mfma_f32_16x16x32_bf16(af[m], bfr[n], acc[m][n], 0, 0, 0);
  }

  // epilogue: D row=(l>>4)*4+reg (maps to A-row/M), col=l&15 (maps to B-row/N)
#pragma unroll
  for (int m = 0; m < 4; ++m)
#pragma unroll
    for (int n = 0; n < 4; ++n)
#pragma unroll
      for (int r = 0; r < 4; ++r) {
        const int row = tm * 128 + wr * 64 + m * 16 + (l >> 4) * 4 + r;
        const int col = tn * 128 + wc * 64 + n * 16 + lr;
        if (OBF) {
          ((unsigned short*)Cv)[bz * strideC + (size_t)row * LDCv + col] =
              f2bf(acc[m][n][r] * scale);
        } else {
          ((float*)Cv)[bz * strideC + (size_t)row * LDCv + col] = acc[m][n][r] * scale;
        }
      }
}

// ---------------- K3: v f32 -> bf16 (no transpose)
__global__ __launch_bounds__(256) void convert_v(
    const float* __restrict__ v, unsigned short* __restrict__ vB) {
  const size_t i8 = (size_t)blockIdx.x * 256 + threadIdx.x;   // 8-element chunk id
  const float4 a = *(const float4*)(v + i8 * 8);
  const float4 b = *(const float4*)(v + i8 * 8 + 4);
  bf16x8 o;
  o[0] = (short)f2bf(a.x); o[1] = (short)f2bf(a.y);
  o[2] = (short)f2bf(a.z); o[3] = (short)f2bf(a.w);
  o[4] = (short)f2bf(b.x); o[5] = (short)f2bf(b.y);
  o[6] = (short)f2bf(b.z); o[7] = (short)f2bf(b.w);
  *(bf16x8*)(vB + i8 * 8) = o;
}

// ---------------- K2: in-place softmax over b (16 values) at each (j,i)
__global__ __launch_bounds__(256) void softmax_b(unsigned short* __restrict__ SP) {
  const size_t off = ((size_t)blockIdx.x * 256 + threadIdx.x) * 8;
  bf16x8 s[BN];
#pragma unroll
  for (int b = 0; b < BN; ++b)
    s[b] = *(const bf16x8*)(SP + (size_t)b * (LN * LN) + off);
#pragma unroll
  for (int e = 0; e < 8; ++e) {
    float vv[BN];
#pragma unroll
    for (int b = 0; b < BN; ++b) vv[b] = bf2f((unsigned short)s[b][e]);
    float m = vv[0];
#pragma unroll
    for (int b = 1; b < BN; ++b) m = fmaxf(m, vv[b]);
    float t[BN], sum = 0.f;
#pragma unroll
    for (int b = 0; b < BN; ++b) { t[b] = __expf(vv[b] - m); sum += t[b]; }
    const float inv = 1.f / sum;
#pragma unroll
    for (int b = 0; b < BN; ++b) s[b][e] = (short)f2bf(t[b] * inv);
  }
#pragma unroll
  for (int b = 0; b < BN; ++b)
    *(bf16x8*)(SP + (size_t)b * (LN * LN) + off) = s[b];
}

extern "C" void kernel_launch(void* const* d_in, const int* in_sizes, int n_in,
                              void* d_out, int out_size, void* d_ws, size_t ws_size,
                              hipStream_t stream) {
  const float* q = (const float*)d_in[0];
  const float* k = (const float*)d_in[1];
  const float* v = (const float*)d_in[2];
  float* out = (float*)d_out;

  unsigned short* qT = (unsigned short*)d_ws;            // 8M elems, 16 MiB
  unsigned short* kT = qT + (size_t)BN * LN * CC;        // 8M elems, 16 MiB
  unsigned short* SP = kT + (size_t)BN * LN * CC;        // 16M elems, 32 MiB (S' then P)
  unsigned short* vB = qT;                               // overlay (qT dead after K1)

  // K0: transpose+convert q,k
  transpose_convert<<<dim3(LN / 32, CC / 32, BN * 2), 256, 0, stream>>>(q, k, qT, kT);
  // K1: S' = (qT . kT^T)/32, bf16. M=N=1024, K=512.
  gemm_bt<512, 512, 512, 1024, true><<<dim3(8, 8, BN), 256, 0, stream>>>(
      qT, kT, (void*)SP, 0.03125f,
      (size_t)LN * CC, (size_t)LN * CC, (size_t)LN * LN);
  // K3: v -> bf16 (overlays qT; qT consumed by K1, stream-ordered)
  convert_v<<<dim3((BN * CC * LN) / 8 / 256), 256, 0, stream>>>(v, vB);
  // K2: softmax over b, in place on SP
  softmax_b<<<dim3((LN * LN) / 8 / 256), 256, 0, stream>>>(SP);
  // K4: out = vB . P^T, f32. M=512, N=1024, K=1024.
  gemm_bt<1024, 1024, 1024, 1024, false><<<dim3(8, 4, BN), 256, 0, stream>>>(
      vB, SP, (void*)out, 1.0f,
      (size_t)CC * LN, (size_t)LN * LN, (size_t)CC * LN);
}

// Round 7
// 100.340 us; speedup vs baseline: 4.1847x; 1.0367x over previous
//
#include <hip/hip_runtime.h>
#include <hip/hip_bf16.h>

// B=16, C=512, L=1024.
// score[b,i,j] = sum_c k[b,c,i]*q[b,c,j] / 32 ; P = softmax over b (axis=0!)
// out[b,c,j] = sum_i v[b,c,i]*P[b,i,j]
// Pipeline (all bf16 MFMA, fp32 accum):
//   K0 transpose_convert: q,k f32 [b][c][l] -> qT,kT bf16 [b][l][c]
//   K1 gemm_glds: S'[b][j][i] = (qT . kT^T)/32, bf16   (batched 1024x1024x512)
//   K3 convert_v: v f32 -> vB bf16 [b][c][i]  (overlays qT, dead after K1)
//   K2 softmax_b: in-place softmax over b (16 per (j,i)) on S'
//   K4 gemm_glds: out[b][c][j] = vB . P^T, f32         (batched 512x1024x1024)
// GEMM structure: 128x128 tile, BK=64, global_load_lds w=16 into linear LDS,
// XOR swizzle slot^=(row&7) on BOTH the global source and the ds_read (rule #21),
// 2-phase double-buffer: STAGE(next) -> ds_read(cur)+MFMA -> barrier.

#define LN 1024
#define CC 512
#define BN 16

typedef __attribute__((ext_vector_type(8))) short bf16x8;
typedef __attribute__((ext_vector_type(4))) float f32x4;

static __device__ __forceinline__ unsigned short f2bf(float x) {
  union { float f; unsigned u; } un; un.f = x;
  unsigned r = un.u + 0x7fffu + ((un.u >> 16) & 1u);   // RNE
  return (unsigned short)(r >> 16);
}
static __device__ __forceinline__ float bf2f(unsigned short h) {
  union { unsigned u; float f; } un; un.u = ((unsigned)h) << 16; return un.f;
}

// ---------------- K0: transpose-convert q,k (f32 [b][c][l]) -> bf16 [b][l][c]
__global__ __launch_bounds__(256) void transpose_convert(
    const float* __restrict__ q, const float* __restrict__ k,
    unsigned short* __restrict__ qT, unsigned short* __restrict__ kT) {
  __shared__ float tile[32][33];
  const int b   = blockIdx.z >> 1;
  const int mat = blockIdx.z & 1;
  const float* src = mat ? k : q;
  unsigned short* dst = mat ? kT : qT;
  const int l0 = blockIdx.x * 32, c0 = blockIdx.y * 32;
  const int t = threadIdx.x;
  const int ll = t & 31, cbase = t >> 5;
  const float* sp = src + ((size_t)b * CC + c0) * LN + l0;
#pragma unroll
  for (int r = 0; r < 4; ++r) {
    int cc = cbase + r * 8;
    tile[cc][ll] = sp[(size_t)cc * LN + ll];
  }
  __syncthreads();
  const int co = t & 31, lbase = t >> 5;
  unsigned short* dp = dst + ((size_t)b * LN + l0) * CC + c0;
#pragma unroll
  for (int r = 0; r < 4; ++r) {
    int lo = lbase + r * 8;
    dp[(size_t)lo * CC + co] = f2bf(tile[co][lo]);
  }
}

// ---------------- batched GEMM, both operands K-contiguous:
// C[row][col] = scale * sum_k A[row][k] * B[col][k]
// 128x128 tile, BK=64 shorts (128B rows), 4 waves 2x2, 4x4 frags of 16x16x32.
template<int KD, int LDAv, int LDBv, int LDCv, bool OBF>
__global__ __launch_bounds__(256) void gemm_glds(
    const unsigned short* __restrict__ A, const unsigned short* __restrict__ B,
    void* __restrict__ Cv, float scale,
    size_t strideA, size_t strideB, size_t strideC) {
  __shared__ unsigned short As[2][128 * 64];   // 2 x 16 KiB
  __shared__ unsigned short Bs[2][128 * 64];   // 2 x 16 KiB  (total 64 KiB)
  const int bz = blockIdx.z;
  const unsigned short* Ab = A + (size_t)bz * strideA;
  const unsigned short* Bb = B + (size_t)bz * strideB;
  const int tm = blockIdx.y, tn = blockIdx.x;
  const int t = threadIdx.x, w = t >> 6, l = t & 63;
  const int wr = w >> 1, wc = w & 1;
  const int lr = l & 15, lks = l >> 4;         // k-slot 0..3 within 32-K step

  f32x4 acc[4][4];
#pragma unroll
  for (int m = 0; m < 4; ++m)
#pragma unroll
    for (int n = 0; n < 4; ++n) acc[m][n] = (f32x4){0.f, 0.f, 0.f, 0.f};

  // staging geometry: thread t covers (row = qq*32 + t/8, slot = t&7) per issue qq.
  // LDS dest linear (wave-uniform base + lane*16); global col pre-swizzled.
  const int srow = t >> 3;        // 0..31
  const int sslot = t & 7;
  const int wvbase = (w * 8) * 64;   // wave-uniform lds short-offset within a qq-chunk

  auto STAGE = [&](int buf, int step) {
    const int c0 = step * 64;
#pragma unroll
    for (int qq = 0; qq < 4; ++qq) {
      const int row = qq * 32 + srow;
      const unsigned short* ga =
          Ab + (size_t)(tm * 128 + row) * LDAv + c0 + ((sslot ^ (row & 7)) * 8);
      __builtin_amdgcn_global_load_lds(
          (const __attribute__((address_space(1))) void*)ga,
          (__attribute__((address_space(3))) void*)&As[buf][qq * 32 * 64 + wvbase],
          16, 0, 0);
    }
#pragma unroll
    for (int qq = 0; qq < 4; ++qq) {
      const int row = qq * 32 + srow;
      const unsigned short* gb =
          Bb + (size_t)(tn * 128 + row) * LDBv + c0 + ((sslot ^ (row & 7)) * 8);
      __builtin_amdgcn_global_load_lds(
          (const __attribute__((address_space(1))) void*)gb,
          (__attribute__((address_space(3))) void*)&Bs[buf][qq * 32 * 64 + wvbase],
          16, 0, 0);
    }
  };

  STAGE(0, 0);
  __syncthreads();   // drains vmcnt(0): buf0 staged

  const int NSTEP = KD / 64;
  int cur = 0;
#pragma unroll 1
  for (int step = 0; step < NSTEP; ++step) {
    if (step + 1 < NSTEP) STAGE(cur ^ 1, step + 1);
#pragma unroll
    for (int kk = 0; kk < 2; ++kk) {
      bf16x8 af[4], bfr[4];
#pragma unroll
      for (int m = 0; m < 4; ++m) {
        const int r = wr * 64 + m * 16 + lr;
        const int slot = (kk * 4 + lks) ^ (r & 7);
        af[m] = *(const bf16x8*)(&As[cur][r * 64 + slot * 8]);
      }
#pragma unroll
      for (int n = 0; n < 4; ++n) {
        const int r = wc * 64 + n * 16 + lr;
        const int slot = (kk * 4 + lks) ^ (r & 7);
        bfr[n] = *(const bf16x8*)(&Bs[cur][r * 64 + slot * 8]);
      }
#pragma unroll
      for (int m = 0; m < 4; ++m)
#pragma unroll
        for (int n = 0; n < 4; ++n)
          acc[m][n] = __builtin_amdgcn_mfma_f32_16x16x32_bf16(af[m], bfr[n], acc[m][n], 0, 0, 0);
    }
    __syncthreads();   // drains next-tile stage (vmcnt 0) + guards buffer reuse
    cur ^= 1;
  }

  // epilogue: D row=(l>>4)*4+reg (M), col=l&15 (N)
#pragma unroll
  for (int m = 0; m < 4; ++m)
#pragma unroll
    for (int n = 0; n < 4; ++n)
#pragma unroll
      for (int r = 0; r < 4; ++r) {
        const int row = tm * 128 + wr * 64 + m * 16 + (l >> 4) * 4 + r;
        const int col = tn * 128 + wc * 64 + n * 16 + lr;
        if (OBF) {
          ((unsigned short*)Cv)[bz * strideC + (size_t)row * LDCv + col] =
              f2bf(acc[m][n][r] * scale);
        } else {
          ((float*)Cv)[bz * strideC + (size_t)row * LDCv + col] = acc[m][n][r] * scale;
        }
      }
}

// ---------------- K3: v f32 -> bf16 (no transpose)
__global__ __launch_bounds__(256) void convert_v(
    const float* __restrict__ v, unsigned short* __restrict__ vB) {
  const size_t i8 = (size_t)blockIdx.x * 256 + threadIdx.x;
  const float4 a = *(const float4*)(v + i8 * 8);
  const float4 b = *(const float4*)(v + i8 * 8 + 4);
  bf16x8 o;
  o[0] = (short)f2bf(a.x); o[1] = (short)f2bf(a.y);
  o[2] = (short)f2bf(a.z); o[3] = (short)f2bf(a.w);
  o[4] = (short)f2bf(b.x); o[5] = (short)f2bf(b.y);
  o[6] = (short)f2bf(b.z); o[7] = (short)f2bf(b.w);
  *(bf16x8*)(vB + i8 * 8) = o;
}

// ---------------- K2: in-place softmax over b (16 values) at each (j,i)
__global__ __launch_bounds__(256) void softmax_b(unsigned short* __restrict__ SP) {
  const size_t off = ((size_t)blockIdx.x * 256 + threadIdx.x) * 8;
  bf16x8 s[BN];
#pragma unroll
  for (int b = 0; b < BN; ++b)
    s[b] = *(const bf16x8*)(SP + (size_t)b * (LN * LN) + off);
#pragma unroll
  for (int e = 0; e < 8; ++e) {
    float vv[BN];
#pragma unroll
    for (int b = 0; b < BN; ++b) vv[b] = bf2f((unsigned short)s[b][e]);
    float m = vv[0];
#pragma unroll
    for (int b = 1; b < BN; ++b) m = fmaxf(m, vv[b]);
    float tt[BN], sum = 0.f;
#pragma unroll
    for (int b = 0; b < BN; ++b) { tt[b] = __expf(vv[b] - m); sum += tt[b]; }
    const float inv = 1.f / sum;
#pragma unroll
    for (int b = 0; b < BN; ++b) s[b][e] = (short)f2bf(tt[b] * inv);
  }
#pragma unroll
  for (int b = 0; b < BN; ++b)
    *(bf16x8*)(SP + (size_t)b * (LN * LN) + off) = s[b];
}

extern "C" void kernel_launch(void* const* d_in, const int* in_sizes, int n_in,
                              void* d_out, int out_size, void* d_ws, size_t ws_size,
                              hipStream_t stream) {
  const float* q = (const float*)d_in[0];
  const float* k = (const float*)d_in[1];
  const float* v = (const float*)d_in[2];
  float* out = (float*)d_out;

  unsigned short* qT = (unsigned short*)d_ws;            // 16 MiB
  unsigned short* kT = qT + (size_t)BN * LN * CC;        // 16 MiB
  unsigned short* SP = kT + (size_t)BN * LN * CC;        // 32 MiB (S' then P)
  unsigned short* vB = qT;                               // overlay (qT dead after K1)

  transpose_convert<<<dim3(LN / 32, CC / 32, BN * 2), 256, 0, stream>>>(q, k, qT, kT);
  // K1: S' = (qT . kT^T)/32, bf16. M=N=1024, K=512.
  gemm_glds<512, 512, 512, 1024, true><<<dim3(8, 8, BN), 256, 0, stream>>>(
      qT, kT, (void*)SP, 0.03125f,
      (size_t)LN * CC, (size_t)LN * CC, (size_t)LN * LN);
  convert_v<<<dim3((BN * CC * LN) / 8 / 256), 256, 0, stream>>>(v, vB);
  softmax_b<<<dim3((LN * LN) / 8 / 256), 256, 0, stream>>>(SP);
  // K4: out = vB . P^T, f32. M=512, N=1024, K=1024.
  gemm_glds<1024, 1024, 1024, 1024, false><<<dim3(8, 4, BN), 256, 0, stream>>>(
      vB, SP, (void*)out, 1.0f,
      (size_t)CC * LN, (size_t)LN * LN, (size_t)CC * LN);
}